// Round 1
// baseline (54.434 us; speedup 1.0000x reference)
//
#include <hip/hip_runtime.h>

// VNCMDLoss: fused masked multi-reduction.
// Inputs (setup_inputs order):
//  0 recon_real  (B,T)   f32
//  1 recon_imag  (B,T)   f32
//  2 target_real (B,T)   f32
//  3 target_imag (B,T)   f32
//  4 eIF         (B,N,T) f32
//  5 target_if   (B,N,T) f32
//  6 mode_mask   (B,N)   i32
// Output: 4 x f32: total_loss, recon_loss, if_loss, smooth_loss

namespace {
constexpr int    kB = 8;
constexpr int    kN = 8;
constexpr int    kT = 262144;
constexpr long long kBT  = (long long)kB * kT;        // 2,097,152
constexpr long long kBNT = (long long)kB * kN * kT;   // 16,777,216

constexpr int THREADS      = 256;
constexpr int RECON_BLOCKS = 512;   // grid-stride over BT/4 = 524288 float4 pairs (4 iters/thread)
constexpr int SEGS         = 32;    // segments per (b,n) row
constexpr int IF_BLOCKS    = kB * kN * SEGS;  // 2048

constexpr double LAMBDA_IF     = 0.5;
constexpr double LAMBDA_SMOOTH = 0.1;
}

// Reduce two float partials across the block, thread 0 atomically adds (as double).
__device__ __forceinline__ void block_atomic_add2(float a, float b,
                                                  double* p0, double* p1) {
    double da = (double)a, db = (double)b;
    #pragma unroll
    for (int o = 32; o > 0; o >>= 1) {
        da += __shfl_down(da, o, 64);
        db += __shfl_down(db, o, 64);
    }
    __shared__ double lds[8];
    const int lane = threadIdx.x & 63;
    const int wid  = threadIdx.x >> 6;      // 4 waves per block
    if (lane == 0) { lds[wid] = da; lds[wid + 4] = db; }
    __syncthreads();
    if (threadIdx.x == 0) {
        atomicAdd(p0, lds[0] + lds[1] + lds[2] + lds[3]);
        atomicAdd(p1, lds[4] + lds[5] + lds[6] + lds[7]);
    }
}

__global__ void init_ws_kernel(double* ws) {
    if (threadIdx.x < 4) ws[threadIdx.x] = 0.0;
}

__global__ __launch_bounds__(THREADS)
void vncmd_main_kernel(const float* __restrict__ rr, const float* __restrict__ ri,
                       const float* __restrict__ tr, const float* __restrict__ ti,
                       const float* __restrict__ eIF, const float* __restrict__ tIF,
                       const int* __restrict__ mask, double* __restrict__ ws) {
    const int bid = blockIdx.x;
    if (bid < RECON_BLOCKS) {
        // ---- recon part: sum (rr-tr)^2 and (ri-ti)^2 over B*T ----
        constexpr int NV = (int)(kBT / 4);   // 524288 float4 per array
        float a0 = 0.f, a1 = 0.f;
        const float4* rr4 = (const float4*)rr;
        const float4* tr4 = (const float4*)tr;
        const float4* ri4 = (const float4*)ri;
        const float4* ti4 = (const float4*)ti;
        for (int v = bid * THREADS + threadIdx.x; v < NV; v += RECON_BLOCKS * THREADS) {
            float4 x = rr4[v], y = tr4[v];
            float d0 = x.x - y.x, d1 = x.y - y.y, d2 = x.z - y.z, d3 = x.w - y.w;
            a0 += d0 * d0 + d1 * d1 + d2 * d2 + d3 * d3;
            float4 u = ri4[v], w = ti4[v];
            float e0 = u.x - w.x, e1 = u.y - w.y, e2 = u.z - w.z, e3 = u.w - w.w;
            a1 += e0 * e0 + e1 * e1 + e2 * e2 + e3 * e3;
        }
        block_atomic_add2(a0, a1, &ws[0], &ws[1]);
    } else {
        // ---- IF part: one block = one (row, segment) ----
        const int ib  = bid - RECON_BLOCKS;
        const int row = ib / SEGS;           // 0..63 = b*N+n
        const int seg = ib % SEGS;
        if (mask[row] != 1) return;          // masked row contributes 0 to both sums; skip reads

        const float* e = eIF + (size_t)row * kT;
        const float* t = tIF + (size_t)row * kT;
        constexpr int VPR = kT / 4;          // 65536 vectors per row
        constexpr int VPS = VPR / SEGS;      // 2048 vectors per segment
        const int v0 = seg * VPS;

        float a2 = 0.f;   // sum (eIF - tIF)^2
        float a3 = 0.f;   // sum (eIF[t+1] - eIF[t])^2
        const float4* e4 = (const float4*)e;
        const float4* t4p = (const float4*)t;
        for (int v = v0 + (int)threadIdx.x; v < v0 + VPS; v += THREADS) {
            const int t4 = v * 4;
            float4 ev = e4[v];
            float4 tv = t4p[v];
            float d0 = ev.x - tv.x, d1 = ev.y - tv.y, d2 = ev.z - tv.z, d3 = ev.w - tv.w;
            a2 += d0 * d0 + d1 * d1 + d2 * d2 + d3 * d3;
            float s0 = ev.y - ev.x, s1 = ev.z - ev.y, s2 = ev.w - ev.z;
            a3 += s0 * s0 + s1 * s1 + s2 * s2;
            if (t4 + 4 < kT) {               // cross-vector diff; overlapping 4B load = L1 hit
                float nx = e[t4 + 4];
                float sb = nx - ev.w;
                a3 += sb * sb;
            }
        }
        block_atomic_add2(a2, a3, &ws[2], &ws[3]);
    }
}

__global__ void finalize_kernel(const double* __restrict__ ws,
                                const int* __restrict__ mask,
                                float* __restrict__ out) {
    const int i = threadIdx.x;  // 64 threads = one wave = B*N entries
    unsigned long long bal = __ballot(mask[i] == 1);
    if (i == 0) {
        double count = (double)__popcll(bal);
        double recon = ws[0] / (double)kBT + ws[1] / (double)kBT;
        double ifl   = ws[2] / (double)kBNT;
        double denom = (count > 1.0 ? count : 1.0) * (double)(kT - 1);
        double smooth = ws[3] / denom;
        double total = recon + LAMBDA_IF * ifl + (count > 0.0 ? LAMBDA_SMOOTH * smooth : 0.0);
        out[0] = (float)total;
        out[1] = (float)recon;
        out[2] = (float)ifl;
        out[3] = (float)smooth;
    }
}

extern "C" void kernel_launch(void* const* d_in, const int* in_sizes, int n_in,
                              void* d_out, int out_size, void* d_ws, size_t ws_size,
                              hipStream_t stream) {
    const float* rr  = (const float*)d_in[0];
    const float* ri  = (const float*)d_in[1];
    const float* tr  = (const float*)d_in[2];
    const float* ti  = (const float*)d_in[3];
    const float* eIF = (const float*)d_in[4];
    const float* tIF = (const float*)d_in[5];
    const int*   msk = (const int*)d_in[6];
    float* out = (float*)d_out;
    double* ws = (double*)d_ws;

    init_ws_kernel<<<1, 64, 0, stream>>>(ws);
    vncmd_main_kernel<<<RECON_BLOCKS + IF_BLOCKS, THREADS, 0, stream>>>(
        rr, ri, tr, ti, eIF, tIF, msk, ws);
    finalize_kernel<<<1, 64, 0, stream>>>(ws, msk, out);
}

// Round 2
// 26.171 us; speedup vs baseline: 2.0800x; 2.0800x over previous
//
#include <hip/hip_runtime.h>

// VNCMDLoss: fused masked multi-reduction, two-stage (no global atomics).
// Inputs (setup_inputs order):
//  0 recon_real  (B,T)   f32
//  1 recon_imag  (B,T)   f32
//  2 target_real (B,T)   f32
//  3 target_imag (B,T)   f32
//  4 eIF         (B,N,T) f32
//  5 target_if   (B,N,T) f32
//  6 mode_mask   (B,N)   i32
// Output: 4 x f32: total_loss, recon_loss, if_loss, smooth_loss
//
// Stage 1: each block reduces its slice and STORES a partial pair to d_ws
//          (no atomics -- FP64 atomicAdd lowers to a contended CAS loop).
// Stage 2: one block reduces the 5120 partials and writes the outputs.

namespace {
constexpr int    kB = 8;
constexpr int    kN = 8;
constexpr int    kT = 262144;
constexpr long long kBT  = (long long)kB * kT;        // 2,097,152
constexpr long long kBNT = (long long)kB * kN * kT;   // 16,777,216

constexpr int THREADS      = 256;
constexpr int RECON_BLOCKS = 512;               // 4 float4-pair iters/thread
constexpr int SEGS         = 32;                // segments per (b,n) row
constexpr int IF_BLOCKS    = kB * kN * SEGS;    // 2048
constexpr int TOTAL_BLOCKS = RECON_BLOCKS + IF_BLOCKS;

constexpr double LAMBDA_IF     = 0.5;
constexpr double LAMBDA_SMOOTH = 0.1;
}

// Reduce two float partials across the block; thread 0 stores both (as double).
__device__ __forceinline__ void block_reduce2_store(float a, float b, double* dst) {
    double da = (double)a, db = (double)b;
    #pragma unroll
    for (int o = 32; o > 0; o >>= 1) {
        da += __shfl_down(da, o, 64);
        db += __shfl_down(db, o, 64);
    }
    __shared__ double lds[8];
    const int lane = threadIdx.x & 63;
    const int wid  = threadIdx.x >> 6;      // 4 waves per block
    if (lane == 0) { lds[wid] = da; lds[wid + 4] = db; }
    __syncthreads();
    if (threadIdx.x == 0) {
        dst[0] = lds[0] + lds[1] + lds[2] + lds[3];
        dst[1] = lds[4] + lds[5] + lds[6] + lds[7];
    }
}

__global__ __launch_bounds__(THREADS)
void vncmd_main_kernel(const float* __restrict__ rr, const float* __restrict__ ri,
                       const float* __restrict__ tr, const float* __restrict__ ti,
                       const float* __restrict__ eIF, const float* __restrict__ tIF,
                       const int* __restrict__ mask, double* __restrict__ ws) {
    const int bid = blockIdx.x;
    if (bid < RECON_BLOCKS) {
        // ---- recon part: sum (rr-tr)^2 and (ri-ti)^2 over B*T ----
        constexpr int NV    = (int)(kBT / 4);                 // 524288 float4 per array
        constexpr int ITERS = NV / (RECON_BLOCKS * THREADS);  // 4, exact
        float a0 = 0.f, a1 = 0.f;
        const float4* rr4 = (const float4*)rr;
        const float4* tr4 = (const float4*)tr;
        const float4* ri4 = (const float4*)ri;
        const float4* ti4 = (const float4*)ti;
        const int base = bid * THREADS + threadIdx.x;
        #pragma unroll
        for (int i = 0; i < ITERS; ++i) {
            const int v = base + i * (RECON_BLOCKS * THREADS);
            float4 x = rr4[v], y = tr4[v];
            float d0 = x.x - y.x, d1 = x.y - y.y, d2 = x.z - y.z, d3 = x.w - y.w;
            a0 += d0 * d0 + d1 * d1 + d2 * d2 + d3 * d3;
            float4 u = ri4[v], w = ti4[v];
            float e0 = u.x - w.x, e1 = u.y - w.y, e2 = u.z - w.z, e3 = u.w - w.w;
            a1 += e0 * e0 + e1 * e1 + e2 * e2 + e3 * e3;
        }
        block_reduce2_store(a0, a1, ws + 2 * bid);
    } else {
        // ---- IF part: one block = one (row, segment) ----
        const int ib  = bid - RECON_BLOCKS;
        const int row = ib / SEGS;           // 0..63 = b*N+n
        const int seg = ib % SEGS;
        double* dst = ws + 2 * RECON_BLOCKS + 2 * ib;
        if (mask[row] != 1) {                // masked row: contributes 0; skip all reads
            if (threadIdx.x == 0) { dst[0] = 0.0; dst[1] = 0.0; }
            return;
        }

        const float* e = eIF + (size_t)row * kT;
        const float* t = tIF + (size_t)row * kT;
        constexpr int VPR   = kT / 4;        // 65536 vectors per row
        constexpr int VPS   = VPR / SEGS;    // 2048 vectors per segment
        constexpr int ITERS = VPS / THREADS; // 8, exact
        const int v0 = seg * VPS;

        float a2 = 0.f;   // sum (eIF - tIF)^2
        float a3 = 0.f;   // sum (eIF[t+1] - eIF[t])^2
        const float4* e4  = (const float4*)e;
        const float4* t4p = (const float4*)t;
        const bool lane63 = (threadIdx.x & 63) == 63;
        #pragma unroll
        for (int i = 0; i < ITERS; ++i) {
            const int v = v0 + i * THREADS + (int)threadIdx.x;
            float4 ev = e4[v];
            float4 tv = t4p[v];
            float d0 = ev.x - tv.x, d1 = ev.y - tv.y, d2 = ev.z - tv.z, d3 = ev.w - tv.w;
            a2 += d0 * d0 + d1 * d1 + d2 * d2 + d3 * d3;
            float s0 = ev.y - ev.x, s1 = ev.z - ev.y, s2 = ev.w - ev.z;
            a3 += s0 * s0 + s1 * s1 + s2 * s2;
            // boundary diff between vector v and v+1: neighbor lane holds ev.x of v+1
            float nx = __shfl_down(ev.x, 1, 64);
            if (lane63 && v + 1 < VPR) nx = e4[v + 1].x;  // wave edge: one scalar load
            if (v + 1 < VPR) {
                float sb = nx - ev.w;
                a3 += sb * sb;
            }
        }
        block_reduce2_store(a2, a3, dst);
    }
}

__global__ __launch_bounds__(THREADS)
void finalize_kernel(const double* __restrict__ ws,
                     const int* __restrict__ mask,
                     float* __restrict__ out) {
    double s0 = 0.0, s1 = 0.0, s2 = 0.0, s3 = 0.0;
    for (int i = threadIdx.x; i < RECON_BLOCKS; i += THREADS) {
        s0 += ws[2 * i];
        s1 += ws[2 * i + 1];
    }
    const double* w2 = ws + 2 * RECON_BLOCKS;
    for (int i = threadIdx.x; i < IF_BLOCKS; i += THREADS) {
        s2 += w2[2 * i];
        s3 += w2[2 * i + 1];
    }
    #pragma unroll
    for (int o = 32; o > 0; o >>= 1) {
        s0 += __shfl_down(s0, o, 64);
        s1 += __shfl_down(s1, o, 64);
        s2 += __shfl_down(s2, o, 64);
        s3 += __shfl_down(s3, o, 64);
    }
    __shared__ double lds[4][4];
    const int lane = threadIdx.x & 63;
    const int wid  = threadIdx.x >> 6;
    if (lane == 0) { lds[wid][0] = s0; lds[wid][1] = s1; lds[wid][2] = s2; lds[wid][3] = s3; }
    __syncthreads();
    if (threadIdx.x == 0) {
        double t0 = lds[0][0] + lds[1][0] + lds[2][0] + lds[3][0];
        double t1 = lds[0][1] + lds[1][1] + lds[2][1] + lds[3][1];
        double t2 = lds[0][2] + lds[1][2] + lds[2][2] + lds[3][2];
        double t3 = lds[0][3] + lds[1][3] + lds[2][3] + lds[3][3];
        int c = 0;
        #pragma unroll
        for (int i = 0; i < kB * kN; ++i) c += (mask[i] == 1);
        double count = (double)c;
        double recon = t0 / (double)kBT + t1 / (double)kBT;
        double ifl   = t2 / (double)kBNT;
        double denom = (count > 1.0 ? count : 1.0) * (double)(kT - 1);
        double smooth = t3 / denom;
        double total = recon + LAMBDA_IF * ifl + (count > 0.0 ? LAMBDA_SMOOTH * smooth : 0.0);
        out[0] = (float)total;
        out[1] = (float)recon;
        out[2] = (float)ifl;
        out[3] = (float)smooth;
    }
}

extern "C" void kernel_launch(void* const* d_in, const int* in_sizes, int n_in,
                              void* d_out, int out_size, void* d_ws, size_t ws_size,
                              hipStream_t stream) {
    const float* rr  = (const float*)d_in[0];
    const float* ri  = (const float*)d_in[1];
    const float* tr  = (const float*)d_in[2];
    const float* ti  = (const float*)d_in[3];
    const float* eIF = (const float*)d_in[4];
    const float* tIF = (const float*)d_in[5];
    const int*   msk = (const int*)d_in[6];
    float* out = (float*)d_out;
    double* ws = (double*)d_ws;

    vncmd_main_kernel<<<TOTAL_BLOCKS, THREADS, 0, stream>>>(
        rr, ri, tr, ti, eIF, tIF, msk, ws);
    finalize_kernel<<<1, THREADS, 0, stream>>>(ws, msk, out);
}